// Round 1
// baseline (1549.438 us; speedup 1.0000x reference)
//
#include <hip/hip_runtime.h>

#define BB 4096
#define LL 100
#define DD 768
#define VV 30522

__global__ __launch_bounds__(192) void sbert_idf_pool_kernel(
    const float* __restrict__ hidden,   // [B, L, D]
    const int*   __restrict__ ids,      // [B, L]
    const int*   __restrict__ mask,     // [B, L]
    const float* __restrict__ idf,      // [V]
    float*       __restrict__ out)      // [B, D]
{
    __shared__ float s_wm[LL];
    __shared__ int   s_msum;

    const int b = blockIdx.x;
    const int t = threadIdx.x;

    if (t == 0) s_msum = 0;
    __syncthreads();

    if (t < LL) {
        const int id = ids[b * LL + t];
        const int m  = mask[b * LL + t];
        s_wm[t] = (m != 0) ? idf[id] : 0.0f;
        if (m != 0) atomicAdd(&s_msum, 1);
    }
    __syncthreads();

    const float inv = 1.0f / fmaxf((float)s_msum, 1e-9f);

    // thread t owns float4 column-group t (D/4 = 192 groups, 192 threads)
    const float4* __restrict__ hrow =
        (const float4*)(hidden + (size_t)b * LL * DD);

    float4 acc = make_float4(0.f, 0.f, 0.f, 0.f);
    #pragma unroll 4
    for (int l = 0; l < LL; ++l) {
        const float  w = s_wm[l];             // wave-uniform broadcast, no conflict
        const float4 h = hrow[l * (DD / 4) + t];  // coalesced 16B/lane
        acc.x += h.x * w;
        acc.y += h.y * w;
        acc.z += h.z * w;
        acc.w += h.w * w;
    }
    acc.x *= inv; acc.y *= inv; acc.z *= inv; acc.w *= inv;

    ((float4*)(out + (size_t)b * DD))[t] = acc;
}

extern "C" void kernel_launch(void* const* d_in, const int* in_sizes, int n_in,
                              void* d_out, int out_size, void* d_ws, size_t ws_size,
                              hipStream_t stream) {
    const float* hidden = (const float*)d_in[0];
    const int*   ids    = (const int*)d_in[1];
    const int*   mask   = (const int*)d_in[2];
    const float* idf    = (const float*)d_in[3];
    float*       out    = (float*)d_out;

    sbert_idf_pool_kernel<<<BB, 192, 0, stream>>>(hidden, ids, mask, idf, out);
}

// Round 2
// 1513.007 us; speedup vs baseline: 1.0241x; 1.0241x over previous
//
#include <hip/hip_runtime.h>

#define BB 4096
#define LL 100
#define DD 768

typedef float v4f __attribute__((ext_vector_type(4)));

__global__ __launch_bounds__(192) void sbert_idf_pool_kernel(
    const float* __restrict__ hidden,   // [B, L, D]
    const int*   __restrict__ ids,      // [B, L]
    const int*   __restrict__ mask,     // [B, L]
    const float* __restrict__ idf,      // [V]
    float*       __restrict__ out)      // [B, D]
{
    __shared__ float s_wm[LL];
    __shared__ int   s_msum;

    const int b = blockIdx.x;
    const int t = threadIdx.x;

    if (t == 0) s_msum = 0;
    __syncthreads();

    if (t < LL) {
        const int id = ids[b * LL + t];
        const int m  = mask[b * LL + t];
        s_wm[t] = (m != 0) ? idf[id] : 0.0f;
        if (m != 0) atomicAdd(&s_msum, 1);
    }
    __syncthreads();

    const float inv = 1.0f / fmaxf((float)s_msum, 1e-9f);

    // thread t owns float4 column-group t (D/4 = 192 groups, 192 threads)
    const v4f* __restrict__ hrow = (const v4f*)(hidden + (size_t)b * LL * DD);

    v4f acc0 = {0.f, 0.f, 0.f, 0.f};
    v4f acc1 = {0.f, 0.f, 0.f, 0.f};

    // 10 nontemporal dwordx4 loads in flight per thread (160 B/lane MLP),
    // two independent FMA chains.
    #pragma unroll
    for (int lb = 0; lb < LL; lb += 10) {
        v4f h[10];
        #pragma unroll
        for (int j = 0; j < 10; ++j)
            h[j] = __builtin_nontemporal_load(&hrow[(lb + j) * (DD / 4) + t]);
        #pragma unroll
        for (int j = 0; j < 10; ++j) {
            const float w = s_wm[lb + j];   // wave-uniform LDS broadcast
            if (j & 1) acc1 += h[j] * w;
            else       acc0 += h[j] * w;
        }
    }

    v4f r = (acc0 + acc1) * inv;
    __builtin_nontemporal_store(r, &((v4f*)(out + (size_t)b * DD))[t]);
}

extern "C" void kernel_launch(void* const* d_in, const int* in_sizes, int n_in,
                              void* d_out, int out_size, void* d_ws, size_t ws_size,
                              hipStream_t stream) {
    const float* hidden = (const float*)d_in[0];
    const int*   ids    = (const int*)d_in[1];
    const int*   mask   = (const int*)d_in[2];
    const float* idf    = (const float*)d_in[3];
    float*       out    = (float*)d_out;

    sbert_idf_pool_kernel<<<BB, 192, 0, stream>>>(hidden, ids, mask, idf, out);
}